// Round 10
// baseline (3987.587 us; speedup 1.0000x reference)
//
#include <hip/hip_runtime.h>
#include <math.h>

#define BATCH 1024
#define HID 256
#define W3 768
#define SLOT (BATCH * HID)

#define NJC (81 * 48)
#define NJP (NJC + 81 * 64)
#define NJT (NJP + 81 * 64)
#define NBLK 768

typedef __bf16 bf16_t;
typedef __bf16 bf16x8 __attribute__((ext_vector_type(8)));
typedef __bf16 bf16x4 __attribute__((ext_vector_type(4)));
typedef float f32x4 __attribute__((ext_vector_type(4)));

__device__ inline bf16x8 cvt8(const float4 a, const float4 b) {
    bf16x8 r;
    r[0] = (bf16_t)a.x; r[1] = (bf16_t)a.y; r[2] = (bf16_t)a.z; r[3] = (bf16_t)a.w;
    r[4] = (bf16_t)b.x; r[5] = (bf16_t)b.y; r[6] = (bf16_t)b.z; r[7] = (bf16_t)b.w;
    return r;
}
__device__ inline bf16x4 cvt4(const float4 a) {
    bf16x4 r;
    r[0] = (bf16_t)a.x; r[1] = (bf16_t)a.y; r[2] = (bf16_t)a.z; r[3] = (bf16_t)a.w;
    return r;
}

// ---------- P0a: Wcpb = bf16(W_cp) ----------
__global__ __launch_bounds__(256) void wcp_conv(
        const float* __restrict__ wcp, bf16_t* __restrict__ wcpb) {
    const size_t n4 = (size_t)81 * HID * W3 / 4;
    size_t i = (size_t)blockIdx.x * 256 + threadIdx.x;
    const size_t nth = (size_t)gridDim.x * 256;
    for (; i < n4; i += nth) {
        const float4 v = *(const float4*)(wcp + i * 4);
        *(bf16x4*)(wcpb + i * 4) = cvt4(v);
    }
}

// ---------- P0b: WhpT[k][m][u] = bf16(W_hp[k][u][m]) ----------
__global__ __launch_bounds__(256) void whp_t_kernel(
        const float* __restrict__ whp, bf16_t* __restrict__ whpT) {
    const int k = blockIdx.z;
    const int m0 = blockIdx.x * 64, u0 = blockIdx.y * 64;
    const int t = threadIdx.x;
    const int tm = t & 63, tg = t >> 6;
    const float* src = whp + (size_t)k * HID * W3;
    bf16_t* dst = whpT + (size_t)k * W3 * HID;
    #pragma unroll
    for (int c = 0; c < 2; ++c) {
        const int ub = u0 + (tg + c * 4) * 8;
        bf16x8 v;
        #pragma unroll
        for (int i = 0; i < 8; ++i)
            v[i] = (bf16_t)src[(size_t)(ub + i) * W3 + m0 + tm];
        *(bf16x8*)(dst + (size_t)(m0 + tm) * HID + ub) = v;
    }
}

// ---------- P1: gvec[k][n4] = Whh[k][n4]·b_hp[k] + b_ih + b_hh ----------
__global__ __launch_bounds__(256) void gvec_kernel(
        const float* __restrict__ Whh, const float* __restrict__ bhp,
        const float* __restrict__ bih, const float* __restrict__ bhh,
        float* __restrict__ gvec) {
    const int k = blockIdx.x, t = threadIdx.x;
    __shared__ float bsm[HID];
    bsm[t] = bhp[(size_t)k * HID + t];
    __syncthreads();
    #pragma unroll
    for (int g = 0; g < 4; ++g) {
        const int n4 = g * HID + t;
        const float* wr = Whh + (size_t)k * 4 * HID * HID + (size_t)n4 * HID;
        float s = 0.f;
        for (int u = 0; u < HID; u += 4) {
            const float4 w = *(const float4*)(wr + u);
            s += w.x * bsm[u] + w.y * bsm[u + 1] + w.z * bsm[u + 2] + w.w * bsm[u + 3];
        }
        gvec[(size_t)k * 1024 + n4] = s + bih[(size_t)k * 1024 + n4]
                                        + bhh[(size_t)k * 1024 + n4];
    }
}

__global__ __launch_bounds__(256) void zero_flags(int* __restrict__ f) {
    if (threadIdx.x < 243) f[threadIdx.x] = 0;
}

// ---------- persistent dataflow kernel: compose -> prevgates -> stage ----
struct MegaArgs {
    const float* h_ext; const float* c_ext;
    const float* grid_h; const float* grid_c;
    const float* Whh; const bf16_t* WhpT; const bf16_t* Wcpb;
    const float* gvec; const float* Wih; const float* bcp; const float* x;
    bf16_t* CC; bf16_t* GP; bf16_t* PP;
    float* gh; float* gc;
    int* Fc; int* Fp; int* Fs;
    int cellorder[81];
};

__global__ __launch_bounds__(256, 4) void mega_kernel(MegaArgs a) {
    __shared__ __align__(16) char smem_raw[33280];
    bf16_t (*A1)[40] = (bf16_t(*)[40])(smem_raw);
    bf16_t (*A2)[40] = (bf16_t(*)[40])(smem_raw + 10240);
    bf16_t (*B1)[40] = (bf16_t(*)[40])(smem_raw + 20480);
    bf16_t (*B2)[40] = (bf16_t(*)[40])(smem_raw + 30720);

    const int t = threadIdx.x;
    const int lane = t & 63, wid = t >> 6;
    const int wm = wid & 1, wn = wid >> 1;
    const int ln = lane & 15, lh = lane >> 4;
    const int sr = t >> 1, sq = (t & 1) * 16;
    const int du2 = t >> 3, kk4 = (t & 7) * 4;

    for (int j = blockIdx.x; j < NJT; j += NBLK) {
        if (j < NJC) {
            // ===== compose: CC[k][c][m], c=by*128+g*32+du =====
            const int r = j / 48, inner = j % 48;
            const int k = a.cellorder[r];
            const int mt = inner % 6, by = inner / 6;
            const int m0 = mt * 128;
            const int g_r = sr >> 5, du_r = sr & 31;
            const float* arow = a.Whh + (size_t)k * 1024 * HID
                                + (size_t)(g_r * HID + by * 32 + du_r) * HID + sq;
            const bf16_t* brow = a.WhpT + (size_t)k * W3 * HID + (size_t)(m0 + sr) * HID + sq;
            f32x4 acc[4][4] = {};
            for (int kb = 0; kb < 8; ++kb) {
                const float4 a0 = *(const float4*)(arow + kb * 32);
                const float4 a1 = *(const float4*)(arow + kb * 32 + 4);
                const float4 a2 = *(const float4*)(arow + kb * 32 + 8);
                const float4 a3 = *(const float4*)(arow + kb * 32 + 12);
                const bf16x8 bv0 = *(const bf16x8*)(brow + kb * 32);
                const bf16x8 bv1 = *(const bf16x8*)(brow + kb * 32 + 8);
                const bf16x8 av0 = cvt8(a0, a1), av1 = cvt8(a2, a3);
                __syncthreads();
                *(bf16x8*)&A1[sr][sq] = av0;
                *(bf16x8*)&A1[sr][sq + 8] = av1;
                *(bf16x8*)&B1[sr][sq] = bv0;
                *(bf16x8*)&B1[sr][sq + 8] = bv1;
                __syncthreads();
                bf16x8 af[4], bfv[4];
                #pragma unroll
                for (int mf = 0; mf < 4; ++mf)
                    af[mf] = *(const bf16x8*)&B1[wm * 64 + mf * 16 + ln][lh * 8];
                #pragma unroll
                for (int cf = 0; cf < 4; ++cf)
                    bfv[cf] = *(const bf16x8*)&A1[wn * 64 + cf * 16 + ln][lh * 8];
                #pragma unroll
                for (int mf = 0; mf < 4; ++mf)
                    #pragma unroll
                    for (int cf = 0; cf < 4; ++cf)
                        acc[mf][cf] = __builtin_amdgcn_mfma_f32_16x16x32_bf16(
                            af[mf], bfv[cf], acc[mf][cf], 0, 0, 0);
            }
            bf16_t* outp = a.CC + (size_t)k * 1024 * W3;
            #pragma unroll
            for (int cf = 0; cf < 4; ++cf) {
                const int c = by * 128 + wn * 64 + cf * 16 + ln;
                #pragma unroll
                for (int mf = 0; mf < 4; ++mf) {
                    const int m = m0 + wm * 64 + mf * 16 + lh * 4;
                    bf16x4 v;
                    #pragma unroll
                    for (int rr = 0; rr < 4; ++rr) v[rr] = (bf16_t)acc[mf][cf][rr];
                    *(bf16x4*)(outp + (size_t)c * W3 + m) = v;
                }
            }
            __syncthreads();
            if (t == 0)
                __hip_atomic_fetch_add(a.Fc + k, 1, __ATOMIC_RELEASE, __HIP_MEMORY_SCOPE_AGENT);
        } else if (j < NJP) {
            // ===== prevgates =====
            const int r = (j - NJC) >> 6, tile = (j - NJC) & 63;
            const int k = a.cellorder[r];
            const int bx = tile & 7, by = tile >> 3;
            const int b0 = bx * 128, u0 = by * 32;
            if (t == 0) {
                while (__hip_atomic_load(a.Fc + k, __ATOMIC_RELAXED, __HIP_MEMORY_SCOPE_AGENT) < 48)
                    __builtin_amdgcn_s_sleep(8);
                __hip_atomic_load(a.Fc + k, __ATOMIC_ACQUIRE, __HIP_MEMORY_SCOPE_AGENT);
            }
            __syncthreads();
            __threadfence();

            const float* ha = a.grid_h + (size_t)k * SLOT + (size_t)(b0 + sr) * HID + sq;
            const float* ca = a.grid_c + (size_t)k * SLOT + (size_t)(b0 + sr) * HID + sq;
            const bf16_t* b1r = a.CC + (size_t)k * 1024 * W3 + (size_t)(by * 128 + sr) * W3 + 512 + sq;
            const bf16_t* b2r = a.Wcpb + (size_t)k * HID * W3 + (size_t)(u0 + du2) * W3 + 512 + kk4;
            f32x4 accg[4][4] = {};
            f32x4 accp[4] = {};
            for (int kb = 0; kb < 8; ++kb) {
                const float4 h0 = *(const float4*)(ha + kb * 32);
                const float4 h1 = *(const float4*)(ha + kb * 32 + 4);
                const float4 h2 = *(const float4*)(ha + kb * 32 + 8);
                const float4 h3 = *(const float4*)(ha + kb * 32 + 12);
                const float4 c0 = *(const float4*)(ca + kb * 32);
                const float4 c1 = *(const float4*)(ca + kb * 32 + 4);
                const float4 c2 = *(const float4*)(ca + kb * 32 + 8);
                const float4 c3 = *(const float4*)(ca + kb * 32 + 12);
                const bf16x8 w0 = *(const bf16x8*)(b1r + kb * 32);
                const bf16x8 w1 = *(const bf16x8*)(b1r + kb * 32 + 8);
                const bf16x4 p0 = *(const bf16x4*)(b2r + kb * 32);
                const bf16x8 hv0 = cvt8(h0, h1), hv1 = cvt8(h2, h3);
                const bf16x8 cv0 = cvt8(c0, c1), cv1 = cvt8(c2, c3);
                __syncthreads();
                *(bf16x8*)&A1[sr][sq] = hv0;  *(bf16x8*)&A1[sr][sq + 8] = hv1;
                *(bf16x8*)&A2[sr][sq] = cv0;  *(bf16x8*)&A2[sr][sq + 8] = cv1;
                *(bf16x8*)&B1[sr][sq] = w0;   *(bf16x8*)&B1[sr][sq + 8] = w1;
                *(bf16x4*)&B2[du2][kk4] = p0;
                __syncthreads();
                bf16x8 af1[4], af2[4], bf1[4], bf2;
                #pragma unroll
                for (int mf = 0; mf < 4; ++mf) {
                    af1[mf] = *(const bf16x8*)&A1[wm * 64 + mf * 16 + ln][lh * 8];
                    af2[mf] = *(const bf16x8*)&A2[wm * 64 + mf * 16 + ln][lh * 8];
                }
                #pragma unroll
                for (int g = 0; g < 4; ++g)
                    bf1[g] = *(const bf16x8*)&B1[g * 32 + wn * 16 + ln][lh * 8];
                bf2 = *(const bf16x8*)&B2[wn * 16 + ln][lh * 8];
                #pragma unroll
                for (int mf = 0; mf < 4; ++mf) {
                    #pragma unroll
                    for (int g = 0; g < 4; ++g)
                        accg[mf][g] = __builtin_amdgcn_mfma_f32_16x16x32_bf16(
                            af1[mf], bf1[g], accg[mf][g], 0, 0, 0);
                    accp[mf] = __builtin_amdgcn_mfma_f32_16x16x32_bf16(
                        af2[mf], bf2, accp[mf], 0, 0, 0);
                }
            }
            const int u = u0 + wn * 16 + ln;
            float wv[4], gv[4];
            #pragma unroll
            for (int g = 0; g < 4; ++g) {
                const int n4 = g * HID + u;
                wv[g] = a.Wih[(size_t)k * 1024 + n4];
                gv[g] = a.gvec[(size_t)k * 1024 + n4];
            }
            const float bc = a.bcp[(size_t)k * HID + u];
            bf16_t* gpb = a.GP + (size_t)k * (BATCH * 1024) + (size_t)tile * 16384;
            bf16_t* ppb = a.PP + (size_t)k * SLOT + (size_t)tile * 4096;
            #pragma unroll
            for (int mf = 0; mf < 4; ++mf) {
                #pragma unroll
                for (int rp = 0; rp < 2; ++rp) {
                    bf16x8 v;
                    #pragma unroll
                    for (int aa = 0; aa < 2; ++aa) {
                        const int rr = rp * 2 + aa;
                        const int b = b0 + wm * 64 + mf * 16 + lh * 4 + rr;
                        const float xv = a.x[(size_t)b * 81 + k];
                        #pragma unroll
                        for (int g = 0; g < 4; ++g)
                            v[aa * 4 + g] = (bf16_t)(accg[mf][g][rr] + gv[g] + xv * wv[g]);
                    }
                    *(bf16x8*)(gpb + (size_t)(mf * 2 + rp) * 2048 + t * 8) = v;
                }
            }
            #pragma unroll
            for (int jj = 0; jj < 2; ++jj) {
                bf16x8 v;
                #pragma unroll
                for (int h2 = 0; h2 < 2; ++h2) {
                    const int mf = jj * 2 + h2;
                    #pragma unroll
                    for (int rr = 0; rr < 4; ++rr)
                        v[h2 * 4 + rr] = (bf16_t)(accp[mf][rr] + bc);
                }
                *(bf16x8*)(ppb + (size_t)jj * 2048 + t * 8) = v;
            }
            __syncthreads();
            if (t == 0)
                __hip_atomic_fetch_add(a.Fp + k, 1, __ATOMIC_RELEASE, __HIP_MEMORY_SCOPE_AGENT);
        } else {
            // ===== stage (wavefront cell) =====
            const int r = (j - NJP) >> 6, tile = (j - NJP) & 63;
            const int k = a.cellorder[r];
            const int ci = k / 9, cj = k % 9;
            const int bx = tile & 7, by = tile >> 3;
            const int b0 = bx * 128, u0 = by * 32;
            const int depL = (cj > 0) ? (k - 1) : -1;
            const int depU = (ci > 0) ? (k - 9) : -1;
            if (t == 0) {
                for (;;) {
                    bool ok = __hip_atomic_load(a.Fc + k, __ATOMIC_RELAXED, __HIP_MEMORY_SCOPE_AGENT) >= 48
                           && __hip_atomic_load(a.Fp + k, __ATOMIC_RELAXED, __HIP_MEMORY_SCOPE_AGENT) >= 64;
                    if (ok && depL >= 0)
                        ok = __hip_atomic_load(a.Fs + depL, __ATOMIC_RELAXED, __HIP_MEMORY_SCOPE_AGENT) >= 64;
                    if (ok && depU >= 0)
                        ok = __hip_atomic_load(a.Fs + depU, __ATOMIC_RELAXED, __HIP_MEMORY_SCOPE_AGENT) >= 64;
                    if (ok) break;
                    __builtin_amdgcn_s_sleep(8);
                }
                __hip_atomic_load(a.Fp + k, __ATOMIC_ACQUIRE, __HIP_MEMORY_SCOPE_AGENT);
            }
            __syncthreads();
            __threadfence();

            const float *hl = nullptr, *cl = nullptr, *hu = nullptr, *cu = nullptr;
            if (ci == 0 && cj == 0) { hl = a.h_ext; cl = a.c_ext; }
            else if (cj > 0) { hl = a.gh + (size_t)(k - 1) * SLOT; cl = a.gc + (size_t)(k - 1) * SLOT; }
            if (ci > 0) { hu = a.gh + (size_t)(k - 9) * SLOT; cu = a.gc + (size_t)(k - 9) * SLOT; }
            const float* hseg[2] = { hl, hu };
            const float* cseg[2] = { cl, cu };

            f32x4 accg[4][4] = {};
            f32x4 accp[4] = {};
            for (int s = 0; s < 2; ++s) {
                const float* hp = hseg[s];
                if (!hp) continue;
                const float* cp = cseg[s];
                const int ko = s * 256;
                const float* ha = hp + (size_t)(b0 + sr) * HID + sq;
                const float* ca = cp + (size_t)(b0 + sr) * HID + sq;
                const bf16_t* b1r = a.CC + (size_t)k * 1024 * W3 + (size_t)(by * 128 + sr) * W3 + ko + sq;
                const bf16_t* b2r = a.Wcpb + (size_t)k * HID * W3 + (size_t)(u0 + du2) * W3 + ko + kk4;
                for (int kb = 0; kb < 8; ++kb) {
                    const float4 h0 = *(const float4*)(ha + kb * 32);
                    const float4 h1 = *(const float4*)(ha + kb * 32 + 4);
                    const float4 h2 = *(const float4*)(ha + kb * 32 + 8);
                    const float4 h3 = *(const float4*)(ha + kb * 32 + 12);
                    const float4 c0 = *(const float4*)(ca + kb * 32);
                    const float4 c1 = *(const float4*)(ca + kb * 32 + 4);
                    const float4 c2 = *(const float4*)(ca + kb * 32 + 8);
                    const float4 c3 = *(const float4*)(ca + kb * 32 + 12);
                    const bf16x8 w0 = *(const bf16x8*)(b1r + kb * 32);
                    const bf16x8 w1 = *(const bf16x8*)(b1r + kb * 32 + 8);
                    const bf16x4 p0 = *(const bf16x4*)(b2r + kb * 32);
                    const bf16x8 hv0 = cvt8(h0, h1), hv1 = cvt8(h2, h3);
                    const bf16x8 cv0 = cvt8(c0, c1), cv1 = cvt8(c2, c3);
                    __syncthreads();
                    *(bf16x8*)&A1[sr][sq] = hv0;  *(bf16x8*)&A1[sr][sq + 8] = hv1;
                    *(bf16x8*)&A2[sr][sq] = cv0;  *(bf16x8*)&A2[sr][sq + 8] = cv1;
                    *(bf16x8*)&B1[sr][sq] = w0;   *(bf16x8*)&B1[sr][sq + 8] = w1;
                    *(bf16x4*)&B2[du2][kk4] = p0;
                    __syncthreads();
                    bf16x8 af1[4], af2[4], bf1[4], bf2;
                    #pragma unroll
                    for (int mf = 0; mf < 4; ++mf) {
                        af1[mf] = *(const bf16x8*)&A1[wm * 64 + mf * 16 + ln][lh * 8];
                        af2[mf] = *(const bf16x8*)&A2[wm * 64 + mf * 16 + ln][lh * 8];
                    }
                    #pragma unroll
                    for (int g = 0; g < 4; ++g)
                        bf1[g] = *(const bf16x8*)&B1[g * 32 + wn * 16 + ln][lh * 8];
                    bf2 = *(const bf16x8*)&B2[wn * 16 + ln][lh * 8];
                    #pragma unroll
                    for (int mf = 0; mf < 4; ++mf) {
                        #pragma unroll
                        for (int g = 0; g < 4; ++g)
                            accg[mf][g] = __builtin_amdgcn_mfma_f32_16x16x32_bf16(
                                af1[mf], bf1[g], accg[mf][g], 0, 0, 0);
                        accp[mf] = __builtin_amdgcn_mfma_f32_16x16x32_bf16(
                            af2[mf], bf2, accp[mf], 0, 0, 0);
                    }
                }
            }
            const int u = u0 + wn * 16 + ln;
            const bf16_t* gpb = a.GP + (size_t)k * (BATCH * 1024) + (size_t)tile * 16384;
            const bf16_t* ppb = a.PP + (size_t)k * SLOT + (size_t)tile * 4096;
            float pcv[4][4];
            #pragma unroll
            for (int jj = 0; jj < 2; ++jj) {
                const bf16x8 v = *(const bf16x8*)(ppb + (size_t)jj * 2048 + t * 8);
                #pragma unroll
                for (int h2 = 0; h2 < 2; ++h2)
                    #pragma unroll
                    for (int rr = 0; rr < 4; ++rr)
                        pcv[jj * 2 + h2][rr] = accp[jj * 2 + h2][rr] + (float)v[h2 * 4 + rr];
            }
            #pragma unroll
            for (int mf = 0; mf < 4; ++mf) {
                #pragma unroll
                for (int rp = 0; rp < 2; ++rp) {
                    const bf16x8 v = *(const bf16x8*)(gpb + (size_t)(mf * 2 + rp) * 2048 + t * 8);
                    #pragma unroll
                    for (int aa = 0; aa < 2; ++aa) {
                        const int rr = rp * 2 + aa;
                        const int b = b0 + wm * 64 + mf * 16 + lh * 4 + rr;
                        const float gi = accg[mf][0][rr] + (float)v[aa * 4 + 0];
                        const float gf = accg[mf][1][rr] + (float)v[aa * 4 + 1];
                        const float gg = accg[mf][2][rr] + (float)v[aa * 4 + 2];
                        const float go = accg[mf][3][rr] + (float)v[aa * 4 + 3];
                        const float pc = pcv[mf][rr];
                        const float i_ = 1.f / (1.f + expf(-gi));
                        const float f_ = 1.f / (1.f + expf(-gf));
                        const float o_ = 1.f / (1.f + expf(-go));
                        const float g_ = tanhf(gg);
                        const float cn = f_ * pc + i_ * g_;
                        const float hn = o_ * tanhf(cn);
                        a.gh[(size_t)(k * SLOT + (size_t)b * HID + u)] = hn;
                        a.gc[(size_t)(k * SLOT + (size_t)b * HID + u)] = cn;
                    }
                }
            }
            __syncthreads();
            if (t == 0)
                __hip_atomic_fetch_add(a.Fs + k, 1, __ATOMIC_RELEASE, __HIP_MEMORY_SCOPE_AGENT);
        }
    }
}

__global__ __launch_bounds__(256) void final_kernel(
        const float* __restrict__ gh88, const float* __restrict__ gc88,
        const float* __restrict__ Wout, const float* __restrict__ bout,
        float* __restrict__ out, float* __restrict__ fh, float* __restrict__ fc) {
    const int tid = blockIdx.x * blockDim.x + threadIdx.x;
    const int nth = gridDim.x * blockDim.x;
    for (int idx = tid; idx < BATCH * HID; idx += nth) {
        fh[idx] = gh88[idx];
        fc[idx] = gc88[idx];
    }
    if (tid < BATCH) {
        float s = bout[0];
        for (int k = 0; k < HID; ++k) s += gh88[(size_t)tid * HID + k] * Wout[k];
        s = fmaxf(s, 0.f);
        out[tid] = 1.f / (1.f + expf(-s));
    }
}

extern "C" void kernel_launch(void* const* d_in, const int* in_sizes, int n_in,
                              void* d_out, int out_size, void* d_ws, size_t ws_size,
                              hipStream_t stream) {
    const float* x      = (const float*)d_in[0];
    const float* h_ext  = (const float*)d_in[1];
    const float* c_ext  = (const float*)d_in[2];
    const float* grid_h = (const float*)d_in[3];
    const float* grid_c = (const float*)d_in[4];
    const float* W_hp   = (const float*)d_in[5];
    const float* b_hp   = (const float*)d_in[6];
    const float* W_cp   = (const float*)d_in[7];
    const float* b_cp   = (const float*)d_in[8];
    const float* W_ih   = (const float*)d_in[9];
    const float* W_hh   = (const float*)d_in[10];
    const float* b_ih   = (const float*)d_in[11];
    const float* b_hh   = (const float*)d_in[12];
    const float* W_out  = (const float*)d_in[13];
    const float* b_out  = (const float*)d_in[14];

    float* out = (float*)d_out;
    float* fh  = out + BATCH * 1;
    float* fc  = fh + SLOT;
    float* gh  = fc + SLOT;
    float* gc  = gh + (size_t)81 * SLOT;

    const size_t wt_b  = (size_t)81 * W3 * HID * 2;
    const size_t wcp_b = (size_t)81 * HID * W3 * 2;
    const size_t cc_b  = (size_t)81 * 1024 * W3 * 2;
    const size_t gp_b  = (size_t)81 * BATCH * 1024 * 2;
    const size_t pp_b  = (size_t)81 * SLOT * 2;
    const size_t gv_b  = (size_t)81 * 1024 * 4;
    const size_t fl_b  = 1024;
    const size_t need = wt_b + wcp_b + cc_b + gp_b + pp_b + gv_b + fl_b;

    char* p = (char*)d_ws;
    bf16_t* WhpT = (bf16_t*)p; p += wt_b;
    bf16_t* Wcpb = (bf16_t*)p; p += wcp_b;
    bf16_t* CC   = (bf16_t*)p; p += cc_b;
    bf16_t* GP   = (bf16_t*)p; p += gp_b;
    bf16_t* PP   = (bf16_t*)p; p += pp_b;
    float*  gvec = (float*)p;  p += gv_b;
    int*    flags = (int*)p;

    (void)need; (void)ws_size;

    wcp_conv<<<dim3(2048), 256, 0, stream>>>(W_cp, Wcpb);
    whp_t_kernel<<<dim3(12, 4, 81), 256, 0, stream>>>(W_hp, WhpT);
    gvec_kernel<<<dim3(81), 256, 0, stream>>>(W_hh, b_hp, b_ih, b_hh, gvec);
    zero_flags<<<dim3(1), 256, 0, stream>>>(flags);

    MegaArgs ma;
    ma.h_ext = h_ext; ma.c_ext = c_ext;
    ma.grid_h = grid_h; ma.grid_c = grid_c;
    ma.Whh = W_hh; ma.WhpT = WhpT; ma.Wcpb = Wcpb;
    ma.gvec = gvec; ma.Wih = W_ih; ma.bcp = b_cp; ma.x = x;
    ma.CC = CC; ma.GP = GP; ma.PP = PP;
    ma.gh = gh; ma.gc = gc;
    ma.Fc = flags; ma.Fp = flags + 81; ma.Fs = flags + 162;
    {
        int idx = 0;
        for (int d = 0; d <= 16; ++d) {
            const int i_lo = d > 8 ? d - 8 : 0;
            const int i_hi = d < 8 ? d : 8;
            for (int i = i_lo; i <= i_hi; ++i)
                ma.cellorder[idx++] = i * 9 + (d - i);
        }
    }
    mega_kernel<<<dim3(NBLK), 256, 0, stream>>>(ma);

    final_kernel<<<dim3(64), 256, 0, stream>>>(
        gh + (size_t)80 * SLOT, gc + (size_t)80 * SLOT,
        W_out, b_out, out, fh, fc);
}